// Round 19
// baseline (79.368 us; speedup 1.0000x reference)
//
#include <hip/hip_runtime.h>
#include <hip/hip_bf16.h>

#define S_LEN 127
#define NB    32
#define HDIM  256
#define DH    64
#define SCALE_F 0.125f

typedef __bf16 bf16x8 __attribute__((ext_vector_type(8)));
typedef __bf16 bf16x4 __attribute__((ext_vector_type(4)));
typedef float  f32x4  __attribute__((ext_vector_type(4)));

#define NTOK  4064                 // NB * S_LEN
#define NW4   16384                // 256*256/4 float4 groups per W

__device__ __forceinline__ float4 b2f4(bf16x4 v) {
  return make_float4((float)v[0], (float)v[1], (float)v[2], (float)v[3]);
}

// ---------------------------------------------------------------------------
// W-only f32 -> bf16 conversion (R8-proven).
// ---------------------------------------------------------------------------
__global__ __launch_bounds__(256) void convert_w(
    const float* __restrict__ Wq, const float* __restrict__ Wk,
    const float* __restrict__ Wv, const float* __restrict__ Wo,
    __bf16* __restrict__ Wqb, __bf16* __restrict__ Wkb,
    __bf16* __restrict__ Wvb, __bf16* __restrict__ Wob)
{
  size_t t = (size_t)blockIdx.x * 256 + threadIdx.x;   // float4 index
  const float* src; __bf16* dst;
  if (t < NW4)                 { src = Wq; dst = Wqb; }
  else if ((t -= NW4) < NW4)   { src = Wk; dst = Wkb; }
  else if ((t -= NW4) < NW4)   { src = Wv; dst = Wvb; }
  else { t -= NW4;               src = Wo; dst = Wob; }
  const float4 x = ((const float4*)src)[t];
  bf16x4 r;
  r[0] = (__bf16)x.x; r[1] = (__bf16)x.y; r[2] = (__bf16)x.z; r[3] = (__bf16)x.w;
  ((bf16x4*)dst)[t] = r;
}

// ---------------------------------------------------------------------------
// q/k/v projection with in-LDS A conversion (R8-proven). grid (127,3), 256 thr.
// ---------------------------------------------------------------------------
__global__ __launch_bounds__(256) void gemm_qkv(
    const float* __restrict__ q_in, const float* __restrict__ k_in,
    const float* __restrict__ v_in,
    const __bf16* __restrict__ Wqb, const float* __restrict__ bq,
    const __bf16* __restrict__ Wkb, const float* __restrict__ bk,
    const __bf16* __restrict__ Wvb, const float* __restrict__ bv,
    __bf16* __restrict__ qpb, __bf16* __restrict__ kpb, __bf16* __restrict__ vpb)
{
  const int tile = blockIdx.x;       // 0..126
  const float* A; const __bf16* W; const float* bias; __bf16* o;
  if (blockIdx.y == 0)      { A = q_in; W = Wqb; bias = bq; o = qpb; }
  else if (blockIdx.y == 1) { A = k_in; W = Wkb; bias = bk; o = kpb; }
  else                      { A = v_in; W = Wvb; bias = bv; o = vpb; }

  __shared__ __bf16 sA[32][264];
  const int row0 = tile * 32;

#pragma unroll
  for (int j = 0; j < 8; ++j) {
    const int f = threadIdx.x + j * 256;   // 0..2047
    const int rr = f >> 6, c4 = f & 63;
    const float4 x = *(const float4*)(A + (size_t)(row0 + rr) * HDIM + c4 * 4);
    __bf16* d = &sA[rr][c4 * 4];
    d[0] = (__bf16)x.x; d[1] = (__bf16)x.y; d[2] = (__bf16)x.z; d[3] = (__bf16)x.w;
  }
  __syncthreads();

  const int w    = threadIdx.x >> 6;
  const int lane = threadIdx.x & 63;
  const int r    = lane & 15;
  const int ksl  = (lane >> 4) << 3;
  const int wc   = w * 64;

  const __bf16* Wb = W + (size_t)(wc + r) * HDIM + ksl;
  f32x4 acc[2][4] = {};

  bf16x8 cw[4];
#pragma unroll
  for (int ni = 0; ni < 4; ++ni)
    cw[ni] = *(const bf16x8*)(Wb + (size_t)ni * 16 * HDIM);
#pragma unroll
  for (int kb = 0; kb < 8; ++kb) {
    bf16x8 nw[4];
    if (kb < 7) {
#pragma unroll
      for (int ni = 0; ni < 4; ++ni)
        nw[ni] = *(const bf16x8*)(Wb + (size_t)ni * 16 * HDIM + (kb + 1) * 32);
    }
    const bf16x8 a0 = *(const bf16x8*)&sA[r][kb * 32 + ksl];
    const bf16x8 a1 = *(const bf16x8*)&sA[16 + r][kb * 32 + ksl];
#pragma unroll
    for (int ni = 0; ni < 4; ++ni) {
      acc[0][ni] = __builtin_amdgcn_mfma_f32_16x16x32_bf16(a0, cw[ni], acc[0][ni], 0, 0, 0);
      acc[1][ni] = __builtin_amdgcn_mfma_f32_16x16x32_bf16(a1, cw[ni], acc[1][ni], 0, 0, 0);
    }
    if (kb < 7) {
#pragma unroll
      for (int ni = 0; ni < 4; ++ni) cw[ni] = nw[ni];
    }
  }
  const int crow = (lane >> 4) * 4;
  const int ccol = lane & 15;
#pragma unroll
  for (int mi = 0; mi < 2; ++mi)
#pragma unroll
    for (int ni = 0; ni < 4; ++ni) {
      const int oc = wc + ni * 16 + ccol;
      const float bv = bias[oc];
#pragma unroll
      for (int rg = 0; rg < 4; ++rg)
        o[(size_t)(row0 + mi * 16 + crow + rg) * HDIM + oc] =
            (__bf16)(acc[mi][ni][rg] + bv);
    }
}

// ---------------------------------------------------------------------------
// Fused sparse attention: exact R18 body, with __launch_bounds__(256, 8) to
// cap VGPR at 64 -> 8 blocks/CU residency (+33% outstanding loads for the
// scattered cold gather).
// ---------------------------------------------------------------------------
__global__ __launch_bounds__(256, 8) void attn_kernel(
    const __bf16* __restrict__ qpb, const __bf16* __restrict__ kpb,
    const __bf16* __restrict__ vpb, const int* __restrict__ graph,
    const float* __restrict__ ekt, const float* __restrict__ evt,
    const float* __restrict__ eqt, __bf16* __restrict__ xpb)
{
  int b, q;
  {
    const int bx = blockIdx.x;
    if (bx < 96) { b = bx / 3; q = bx % 3; }
    else { const int rr = bx - 96; b = rr / 124; q = 3 + rr % 124; }
  }
  const int t = threadIdx.x;
  const int w = t >> 6;        // wave 0..3
  const int l = t & 63;        // lane
  const int ll = l & 15;       // d-group: d = ll*4 .. ll*4+3
  const int g  = l >> 4;       // column slot 0..3

  __shared__ int   s_list[S_LEN];
  __shared__ float s_attn[4][S_LEN];
  __shared__ int   s_cnt[2];

  // ---- hoisted: q-row loads + base pointers (independent of s_list) ----
  const __bf16* qrow = qpb + ((size_t)b * S_LEN + q) * HDIM;
  float4 q4[4];
#pragma unroll
  for (int h = 0; h < 4; ++h)
    q4[h] = b2f4(*(const bf16x4*)(qrow + h * 64 + ll * 4));
  const float* eqb2 = eqt + ((size_t)b * S_LEN * S_LEN + q) * DH;
  const float* ekb2 = ekt + ((size_t)(b * S_LEN + q)) * S_LEN * DH;
  const float* evb2 = evt + ((size_t)(b * S_LEN + q)) * S_LEN * DH;
  const __bf16* kpbb = kpb + (size_t)b * S_LEN * HDIM;

  // ---- compacted valid-k list ----
  bool valid = false;
  const int k0 = w * 64 + l;
  if (w < 2 && k0 < S_LEN) {
    const int gr = graph[((size_t)b * S_LEN + q) * S_LEN + k0];
    bool keep;
    if (q < 3 || k0 < 3) keep = true;
    else {
      const int blk = 3 + 2 * ((q - 3) >> 1);
      keep = (k0 >= blk) & (k0 < blk + 2);
    }
    valid = (gr != 0) && keep;
  }
  const unsigned long long bal = __ballot(valid);
  if (w < 2 && l == 0) s_cnt[w] = (int)__popcll(bal);
  __syncthreads();
  int n = s_cnt[0] + s_cnt[1];
  if (valid) {
    const int pos = (int)__popcll(bal & ((1ull << l) - 1ull)) + (w ? s_cnt[0] : 0);
    s_list[pos] = k0;
  }
  __syncthreads();

  if (n == 0) {
    if (t < S_LEN) {
      s_list[t] = t;
      const float u = 1.0f / 127.0f;
      s_attn[0][t] = u; s_attn[1][t] = u; s_attn[2][t] = u; s_attn[3][t] = u;
    }
    n = S_LEN;
  } else {
    // ---- scores: group (w,g) owns column i0 + w*4 + g, 1-deep prefetch ----
    const int myi = w * 4 + g;

    float4 ceq, cek;
    bf16x4 ck0, ck1, ck2, ck3;
    if (myi < n) {
      const int kk = s_list[myi];
      ceq = *(const float4*)(eqb2 + (size_t)kk * (S_LEN * DH) + ll * 4);
      cek = *(const float4*)(ekb2 + kk * DH + ll * 4);
      const __bf16* kr = kpbb + (size_t)kk * HDIM + ll * 4;
      ck0 = *(const bf16x4*)(kr);
      ck1 = *(const bf16x4*)(kr + 64);
      ck2 = *(const bf16x4*)(kr + 128);
      ck3 = *(const bf16x4*)(kr + 192);
    }
    for (int i0 = 0; i0 < n; i0 += 16) {
      const int i = i0 + myi;
      float4 neq, nek;
      bf16x4 nk0, nk1, nk2, nk3;
      const int j = i + 16;
      if (j < n) {
        const int kk = s_list[j];
        neq = *(const float4*)(eqb2 + (size_t)kk * (S_LEN * DH) + ll * 4);
        nek = *(const float4*)(ekb2 + kk * DH + ll * 4);
        const __bf16* kr = kpbb + (size_t)kk * HDIM + ll * 4;
        nk0 = *(const bf16x4*)(kr);
        nk1 = *(const bf16x4*)(kr + 64);
        nk2 = *(const bf16x4*)(kr + 128);
        nk3 = *(const bf16x4*)(kr + 192);
      }
      float p0 = 0.f, p1 = 0.f, p2 = 0.f, p3 = 0.f;
      if (i < n) {
        const float4 k0f = b2f4(ck0), k1f = b2f4(ck1),
                     k2f = b2f4(ck2), k3f = b2f4(ck3);
        p0 = (q4[0].x+ceq.x)*(k0f.x+cek.x) + (q4[0].y+ceq.y)*(k0f.y+cek.y)
           + (q4[0].z+ceq.z)*(k0f.z+cek.z) + (q4[0].w+ceq.w)*(k0f.w+cek.w);
        p1 = (q4[1].x+ceq.x)*(k1f.x+cek.x) + (q4[1].y+ceq.y)*(k1f.y+cek.y)
           + (q4[1].z+ceq.z)*(k1f.z+cek.z) + (q4[1].w+ceq.w)*(k1f.w+cek.w);
        p2 = (q4[2].x+ceq.x)*(k2f.x+cek.x) + (q4[2].y+ceq.y)*(k2f.y+cek.y)
           + (q4[2].z+ceq.z)*(k2f.z+cek.z) + (q4[2].w+ceq.w)*(k2f.w+cek.w);
        p3 = (q4[3].x+ceq.x)*(k3f.x+cek.x) + (q4[3].y+ceq.y)*(k3f.y+cek.y)
           + (q4[3].z+ceq.z)*(k3f.z+cek.z) + (q4[3].w+ceq.w)*(k3f.w+cek.w);
      }
#pragma unroll
      for (int off = 1; off < 16; off <<= 1) {
        p0 += __shfl_xor(p0, off, 64);
        p1 += __shfl_xor(p1, off, 64);
        p2 += __shfl_xor(p2, off, 64);
        p3 += __shfl_xor(p3, off, 64);
      }
      if (i < n && ll < 4) {
        const float sc = (ll == 0) ? p0 : (ll == 1) ? p1 : (ll == 2) ? p2 : p3;
        s_attn[ll][i] = sc * SCALE_F;
      }
      ceq = neq; cek = nek;
      ck0 = nk0; ck1 = nk1; ck2 = nk2; ck3 = nk3;
    }
    __syncthreads();

    // ---- softmax per head ----
    {
      const float v0 = (l < n) ? s_attn[w][l] : -INFINITY;
      const float v1 = (64 + l < n) ? s_attn[w][64 + l] : -INFINITY;
      float mx = fmaxf(v0, v1);
#pragma unroll
      for (int off = 32; off; off >>= 1) mx = fmaxf(mx, __shfl_xor(mx, off, 64));
      const float e0 = (l < n) ? expf(v0 - mx) : 0.f;
      const float e1 = (64 + l < n) ? expf(v1 - mx) : 0.f;
      float sm = e0 + e1;
#pragma unroll
      for (int off = 32; off; off >>= 1) sm += __shfl_xor(sm, off, 64);
      const float inv = 1.0f / sm;
      if (l < n) s_attn[w][l] = e0 * inv;
      if (64 + l < n) s_attn[w][64 + l] = e1 * inv;
    }
  }
  __syncthreads();

  // ---- PV: wave w = head w; group g owns columns g, g+4, ...; 8-deep batch ----
  {
    const __bf16* vbp = vpb + (size_t)b * S_LEN * HDIM + w * DH + ll * 4;
    float ax = 0.f, ay = 0.f, az = 0.f, aw2 = 0.f;

    for (int i0 = g; i0 < n; i0 += 32) {   // 8 slots x stride 4
      float  a8[8];
      bf16x4 v8[8];
      float4 e8[8];
#pragma unroll
      for (int s = 0; s < 8; ++s) {
        const int i = i0 + s * 4;
        if (i < n) {
          const int kk = s_list[i];
          a8[s] = s_attn[w][i];
          v8[s] = *(const bf16x4*)(vbp + (size_t)kk * HDIM);
          e8[s] = *(const float4*)(evb2 + kk * DH + ll * 4);
        } else {
          a8[s] = 0.f;
          v8[s] = bf16x4{};
          e8[s] = make_float4(0.f, 0.f, 0.f, 0.f);
        }
      }
#pragma unroll
      for (int s = 0; s < 8; ++s) {
        const float4 vf = b2f4(v8[s]);
        ax  += a8[s] * (vf.x + e8[s].x);
        ay  += a8[s] * (vf.y + e8[s].y);
        az  += a8[s] * (vf.z + e8[s].z);
        aw2 += a8[s] * (vf.w + e8[s].w);
      }
    }
#pragma unroll
    for (int off = 16; off < 64; off <<= 1) {
      ax  += __shfl_xor(ax, off, 64);
      ay  += __shfl_xor(ay, off, 64);
      az  += __shfl_xor(az, off, 64);
      aw2 += __shfl_xor(aw2, off, 64);
    }
    if (g == 0) {
      bf16x4 rr;
      rr[0] = (__bf16)ax; rr[1] = (__bf16)ay;
      rr[2] = (__bf16)az; rr[3] = (__bf16)aw2;
      *(bf16x4*)(xpb + ((size_t)b * S_LEN + q) * HDIM + w * 64 + ll * 4) = rr;
    }
  }
}

// ---------------------------------------------------------------------------
// Output projection (R8-proven): per-wave 32x32 tile, bf16 A and W.
// ---------------------------------------------------------------------------
__global__ __launch_bounds__(256) void gemm_o(
    const __bf16* __restrict__ A, const __bf16* __restrict__ W,
    const float* __restrict__ bias, float* __restrict__ out)
{
  const int w = threadIdx.x >> 6;
  const int tile = blockIdx.x * 4 + w;
  if (tile >= 127) return;
  const int row0 = tile * 32, col0 = blockIdx.y * 32;
  const int lane = threadIdx.x & 63;
  const int r  = lane & 15;
  const int ks = (lane >> 4) << 3;
  const __bf16* Ab = A + (size_t)(row0 + r) * HDIM + ks;
  const __bf16* Wb = W + (size_t)(col0 + r) * HDIM + ks;
  f32x4 acc[2][2] = {};

  bf16x8 ca[2], cw[2];
  ca[0] = *(const bf16x8*)Ab;
  ca[1] = *(const bf16x8*)(Ab + (size_t)16 * HDIM);
  cw[0] = *(const bf16x8*)Wb;
  cw[1] = *(const bf16x8*)(Wb + (size_t)16 * HDIM);
#pragma unroll
  for (int kb = 0; kb < 8; ++kb) {
    bf16x8 na[2], nw[2];
    if (kb < 7) {
      const int off = (kb + 1) * 32;
      na[0] = *(const bf16x8*)(Ab + off);
      na[1] = *(const bf16x8*)(Ab + (size_t)16 * HDIM + off);
      nw[0] = *(const bf16x8*)(Wb + off);
      nw[1] = *(const bf16x8*)(Wb + (size_t)16 * HDIM + off);
    }
#pragma unroll
    for (int mi = 0; mi < 2; ++mi)
#pragma unroll
      for (int ni = 0; ni < 2; ++ni)
        acc[mi][ni] = __builtin_amdgcn_mfma_f32_16x16x32_bf16(
            ca[mi], cw[ni], acc[mi][ni], 0, 0, 0);
    if (kb < 7) {
      ca[0] = na[0]; ca[1] = na[1];
      cw[0] = nw[0]; cw[1] = nw[1];
    }
  }
  const int crow = (lane >> 4) * 4;
  const int ccol = lane & 15;
#pragma unroll
  for (int mi = 0; mi < 2; ++mi)
#pragma unroll
    for (int ni = 0; ni < 2; ++ni) {
      const int oc = col0 + ni * 16 + ccol;
      const float bv = bias[oc];
#pragma unroll
      for (int rg = 0; rg < 4; ++rg)
        out[(size_t)(row0 + mi * 16 + crow + rg) * HDIM + oc] = acc[mi][ni][rg] + bv;
    }
}

extern "C" void kernel_launch(void* const* d_in, const int* in_sizes, int n_in,
                              void* d_out, int out_size, void* d_ws, size_t ws_size,
                              hipStream_t stream) {
  const float* query = (const float*)d_in[0];
  const float* key   = (const float*)d_in[1];
  const float* value = (const float*)d_in[2];
  const int*   graph = (const int*)d_in[3];
  const float* ekt   = (const float*)d_in[4];
  const float* evt   = (const float*)d_in[5];
  const float* eqt   = (const float*)d_in[6];
  const float* Wq = (const float*)d_in[7];  const float* bq = (const float*)d_in[8];
  const float* Wk = (const float*)d_in[9];  const float* bk = (const float*)d_in[10];
  const float* Wv = (const float*)d_in[11]; const float* bv = (const float*)d_in[12];
  const float* Wo = (const float*)d_in[13]; const float* bo = (const float*)d_in[14];
  float* out = (float*)d_out;

  const size_t NE = (size_t)NTOK * HDIM;   // 1,040,384 elems
  char* p = (char*)d_ws;
  __bf16* qpb = (__bf16*)p;         p += NE * 2;
  __bf16* kpb = (__bf16*)p;         p += NE * 2;
  __bf16* vpb = (__bf16*)p;         p += NE * 2;
  __bf16* xpb = (__bf16*)p;         p += NE * 2;
  __bf16* Wqb = (__bf16*)p;         p += (size_t)HDIM * HDIM * 2;
  __bf16* Wkb = (__bf16*)p;         p += (size_t)HDIM * HDIM * 2;
  __bf16* Wvb = (__bf16*)p;         p += (size_t)HDIM * HDIM * 2;
  __bf16* Wob = (__bf16*)p;

  convert_w<<<dim3(256), 256, 0, stream>>>(Wq, Wk, Wv, Wo, Wqb, Wkb, Wvb, Wob);
  gemm_qkv<<<dim3(127, 3), 256, 0, stream>>>(query, key, value,
                                             Wqb, bq, Wkb, bk, Wvb, bv,
                                             qpb, kpb, vpb);
  attn_kernel<<<dim3(NB * S_LEN), 256, 0, stream>>>(qpb, kpb, vpb, graph,
                                                    ekt, evt, eqt, xpb);
  gemm_o<<<dim3(32, 8), 256, 0, stream>>>(xpb, Wob, bo, out);
}

// Round 20
// 46.074 us; speedup vs baseline: 1.7226x; 1.7226x over previous
//
#include <hip/hip_runtime.h>
#include <hip/hip_bf16.h>

#define S_LEN 127
#define NB    32
#define HDIM  256
#define DH    64
#define SCALE_F 0.125f

typedef __bf16 bf16x8 __attribute__((ext_vector_type(8)));
typedef __bf16 bf16x4 __attribute__((ext_vector_type(4)));
typedef float  f32x4  __attribute__((ext_vector_type(4)));

#define NTOK  4064                 // NB * S_LEN
#define NW4   16384                // 256*256/4 float4 groups per W

__device__ __forceinline__ float4 b2f4(bf16x4 v) {
  return make_float4((float)v[0], (float)v[1], (float)v[2], (float)v[3]);
}

// ---------------------------------------------------------------------------
// W-only f32 -> bf16 conversion (R8-proven).
// ---------------------------------------------------------------------------
__global__ __launch_bounds__(256) void convert_w(
    const float* __restrict__ Wq, const float* __restrict__ Wk,
    const float* __restrict__ Wv, const float* __restrict__ Wo,
    __bf16* __restrict__ Wqb, __bf16* __restrict__ Wkb,
    __bf16* __restrict__ Wvb, __bf16* __restrict__ Wob)
{
  size_t t = (size_t)blockIdx.x * 256 + threadIdx.x;   // float4 index
  const float* src; __bf16* dst;
  if (t < NW4)                 { src = Wq; dst = Wqb; }
  else if ((t -= NW4) < NW4)   { src = Wk; dst = Wkb; }
  else if ((t -= NW4) < NW4)   { src = Wv; dst = Wvb; }
  else { t -= NW4;               src = Wo; dst = Wob; }
  const float4 x = ((const float4*)src)[t];
  bf16x4 r;
  r[0] = (__bf16)x.x; r[1] = (__bf16)x.y; r[2] = (__bf16)x.z; r[3] = (__bf16)x.w;
  ((bf16x4*)dst)[t] = r;
}

// ---------------------------------------------------------------------------
// q/k/v projection with in-LDS A conversion (R8-proven). grid (127,3), 256 thr.
// ---------------------------------------------------------------------------
__global__ __launch_bounds__(256) void gemm_qkv(
    const float* __restrict__ q_in, const float* __restrict__ k_in,
    const float* __restrict__ v_in,
    const __bf16* __restrict__ Wqb, const float* __restrict__ bq,
    const __bf16* __restrict__ Wkb, const float* __restrict__ bk,
    const __bf16* __restrict__ Wvb, const float* __restrict__ bv,
    __bf16* __restrict__ qpb, __bf16* __restrict__ kpb, __bf16* __restrict__ vpb)
{
  const int tile = blockIdx.x;       // 0..126
  const float* A; const __bf16* W; const float* bias; __bf16* o;
  if (blockIdx.y == 0)      { A = q_in; W = Wqb; bias = bq; o = qpb; }
  else if (blockIdx.y == 1) { A = k_in; W = Wkb; bias = bk; o = kpb; }
  else                      { A = v_in; W = Wvb; bias = bv; o = vpb; }

  __shared__ __bf16 sA[32][264];
  const int row0 = tile * 32;

#pragma unroll
  for (int j = 0; j < 8; ++j) {
    const int f = threadIdx.x + j * 256;   // 0..2047
    const int rr = f >> 6, c4 = f & 63;
    const float4 x = *(const float4*)(A + (size_t)(row0 + rr) * HDIM + c4 * 4);
    __bf16* d = &sA[rr][c4 * 4];
    d[0] = (__bf16)x.x; d[1] = (__bf16)x.y; d[2] = (__bf16)x.z; d[3] = (__bf16)x.w;
  }
  __syncthreads();

  const int w    = threadIdx.x >> 6;
  const int lane = threadIdx.x & 63;
  const int r    = lane & 15;
  const int ksl  = (lane >> 4) << 3;
  const int wc   = w * 64;

  const __bf16* Wb = W + (size_t)(wc + r) * HDIM + ksl;
  f32x4 acc[2][4] = {};

  bf16x8 cw[4];
#pragma unroll
  for (int ni = 0; ni < 4; ++ni)
    cw[ni] = *(const bf16x8*)(Wb + (size_t)ni * 16 * HDIM);
#pragma unroll
  for (int kb = 0; kb < 8; ++kb) {
    bf16x8 nw[4];
    if (kb < 7) {
#pragma unroll
      for (int ni = 0; ni < 4; ++ni)
        nw[ni] = *(const bf16x8*)(Wb + (size_t)ni * 16 * HDIM + (kb + 1) * 32);
    }
    const bf16x8 a0 = *(const bf16x8*)&sA[r][kb * 32 + ksl];
    const bf16x8 a1 = *(const bf16x8*)&sA[16 + r][kb * 32 + ksl];
#pragma unroll
    for (int ni = 0; ni < 4; ++ni) {
      acc[0][ni] = __builtin_amdgcn_mfma_f32_16x16x32_bf16(a0, cw[ni], acc[0][ni], 0, 0, 0);
      acc[1][ni] = __builtin_amdgcn_mfma_f32_16x16x32_bf16(a1, cw[ni], acc[1][ni], 0, 0, 0);
    }
    if (kb < 7) {
#pragma unroll
      for (int ni = 0; ni < 4; ++ni) cw[ni] = nw[ni];
    }
  }
  const int crow = (lane >> 4) * 4;
  const int ccol = lane & 15;
#pragma unroll
  for (int mi = 0; mi < 2; ++mi)
#pragma unroll
    for (int ni = 0; ni < 4; ++ni) {
      const int oc = wc + ni * 16 + ccol;
      const float bv = bias[oc];
#pragma unroll
      for (int rg = 0; rg < 4; ++rg)
        o[(size_t)(row0 + mi * 16 + crow + rg) * HDIM + oc] =
            (__bf16)(acc[mi][ni][rg] + bv);
    }
}

// ---------------------------------------------------------------------------
// Fused sparse attention (R18 champion): hoisted q4/base pointers, 1-deep
// prefetched scores, 8-deep batched PV. Natural VGPR (76), no launch bound
// beyond 256 threads.
// ---------------------------------------------------------------------------
__global__ __launch_bounds__(256) void attn_kernel(
    const __bf16* __restrict__ qpb, const __bf16* __restrict__ kpb,
    const __bf16* __restrict__ vpb, const int* __restrict__ graph,
    const float* __restrict__ ekt, const float* __restrict__ evt,
    const float* __restrict__ eqt, __bf16* __restrict__ xpb)
{
  int b, q;
  {
    const int bx = blockIdx.x;
    if (bx < 96) { b = bx / 3; q = bx % 3; }
    else { const int rr = bx - 96; b = rr / 124; q = 3 + rr % 124; }
  }
  const int t = threadIdx.x;
  const int w = t >> 6;        // wave 0..3
  const int l = t & 63;        // lane
  const int ll = l & 15;       // d-group: d = ll*4 .. ll*4+3
  const int g  = l >> 4;       // column slot 0..3

  __shared__ int   s_list[S_LEN];
  __shared__ float s_attn[4][S_LEN];
  __shared__ int   s_cnt[2];

  // ---- hoisted: q-row loads + base pointers (independent of s_list) ----
  const __bf16* qrow = qpb + ((size_t)b * S_LEN + q) * HDIM;
  float4 q4[4];
#pragma unroll
  for (int h = 0; h < 4; ++h)
    q4[h] = b2f4(*(const bf16x4*)(qrow + h * 64 + ll * 4));
  const float* eqb2 = eqt + ((size_t)b * S_LEN * S_LEN + q) * DH;
  const float* ekb2 = ekt + ((size_t)(b * S_LEN + q)) * S_LEN * DH;
  const float* evb2 = evt + ((size_t)(b * S_LEN + q)) * S_LEN * DH;
  const __bf16* kpbb = kpb + (size_t)b * S_LEN * HDIM;

  // ---- compacted valid-k list ----
  bool valid = false;
  const int k0 = w * 64 + l;
  if (w < 2 && k0 < S_LEN) {
    const int gr = graph[((size_t)b * S_LEN + q) * S_LEN + k0];
    bool keep;
    if (q < 3 || k0 < 3) keep = true;
    else {
      const int blk = 3 + 2 * ((q - 3) >> 1);
      keep = (k0 >= blk) & (k0 < blk + 2);
    }
    valid = (gr != 0) && keep;
  }
  const unsigned long long bal = __ballot(valid);
  if (w < 2 && l == 0) s_cnt[w] = (int)__popcll(bal);
  __syncthreads();
  int n = s_cnt[0] + s_cnt[1];
  if (valid) {
    const int pos = (int)__popcll(bal & ((1ull << l) - 1ull)) + (w ? s_cnt[0] : 0);
    s_list[pos] = k0;
  }
  __syncthreads();

  if (n == 0) {
    if (t < S_LEN) {
      s_list[t] = t;
      const float u = 1.0f / 127.0f;
      s_attn[0][t] = u; s_attn[1][t] = u; s_attn[2][t] = u; s_attn[3][t] = u;
    }
    n = S_LEN;
  } else {
    // ---- scores: group (w,g) owns column i0 + w*4 + g, 1-deep prefetch ----
    const int myi = w * 4 + g;

    float4 ceq, cek;
    bf16x4 ck0, ck1, ck2, ck3;
    if (myi < n) {
      const int kk = s_list[myi];
      ceq = *(const float4*)(eqb2 + (size_t)kk * (S_LEN * DH) + ll * 4);
      cek = *(const float4*)(ekb2 + kk * DH + ll * 4);
      const __bf16* kr = kpbb + (size_t)kk * HDIM + ll * 4;
      ck0 = *(const bf16x4*)(kr);
      ck1 = *(const bf16x4*)(kr + 64);
      ck2 = *(const bf16x4*)(kr + 128);
      ck3 = *(const bf16x4*)(kr + 192);
    }
    for (int i0 = 0; i0 < n; i0 += 16) {
      const int i = i0 + myi;
      float4 neq, nek;
      bf16x4 nk0, nk1, nk2, nk3;
      const int j = i + 16;
      if (j < n) {
        const int kk = s_list[j];
        neq = *(const float4*)(eqb2 + (size_t)kk * (S_LEN * DH) + ll * 4);
        nek = *(const float4*)(ekb2 + kk * DH + ll * 4);
        const __bf16* kr = kpbb + (size_t)kk * HDIM + ll * 4;
        nk0 = *(const bf16x4*)(kr);
        nk1 = *(const bf16x4*)(kr + 64);
        nk2 = *(const bf16x4*)(kr + 128);
        nk3 = *(const bf16x4*)(kr + 192);
      }
      float p0 = 0.f, p1 = 0.f, p2 = 0.f, p3 = 0.f;
      if (i < n) {
        const float4 k0f = b2f4(ck0), k1f = b2f4(ck1),
                     k2f = b2f4(ck2), k3f = b2f4(ck3);
        p0 = (q4[0].x+ceq.x)*(k0f.x+cek.x) + (q4[0].y+ceq.y)*(k0f.y+cek.y)
           + (q4[0].z+ceq.z)*(k0f.z+cek.z) + (q4[0].w+ceq.w)*(k0f.w+cek.w);
        p1 = (q4[1].x+ceq.x)*(k1f.x+cek.x) + (q4[1].y+ceq.y)*(k1f.y+cek.y)
           + (q4[1].z+ceq.z)*(k1f.z+cek.z) + (q4[1].w+ceq.w)*(k1f.w+cek.w);
        p2 = (q4[2].x+ceq.x)*(k2f.x+cek.x) + (q4[2].y+ceq.y)*(k2f.y+cek.y)
           + (q4[2].z+ceq.z)*(k2f.z+cek.z) + (q4[2].w+ceq.w)*(k2f.w+cek.w);
        p3 = (q4[3].x+ceq.x)*(k3f.x+cek.x) + (q4[3].y+ceq.y)*(k3f.y+cek.y)
           + (q4[3].z+ceq.z)*(k3f.z+cek.z) + (q4[3].w+ceq.w)*(k3f.w+cek.w);
      }
#pragma unroll
      for (int off = 1; off < 16; off <<= 1) {
        p0 += __shfl_xor(p0, off, 64);
        p1 += __shfl_xor(p1, off, 64);
        p2 += __shfl_xor(p2, off, 64);
        p3 += __shfl_xor(p3, off, 64);
      }
      if (i < n && ll < 4) {
        const float sc = (ll == 0) ? p0 : (ll == 1) ? p1 : (ll == 2) ? p2 : p3;
        s_attn[ll][i] = sc * SCALE_F;
      }
      ceq = neq; cek = nek;
      ck0 = nk0; ck1 = nk1; ck2 = nk2; ck3 = nk3;
    }
    __syncthreads();

    // ---- softmax per head ----
    {
      const float v0 = (l < n) ? s_attn[w][l] : -INFINITY;
      const float v1 = (64 + l < n) ? s_attn[w][64 + l] : -INFINITY;
      float mx = fmaxf(v0, v1);
#pragma unroll
      for (int off = 32; off; off >>= 1) mx = fmaxf(mx, __shfl_xor(mx, off, 64));
      const float e0 = (l < n) ? expf(v0 - mx) : 0.f;
      const float e1 = (64 + l < n) ? expf(v1 - mx) : 0.f;
      float sm = e0 + e1;
#pragma unroll
      for (int off = 32; off; off >>= 1) sm += __shfl_xor(sm, off, 64);
      const float inv = 1.0f / sm;
      if (l < n) s_attn[w][l] = e0 * inv;
      if (64 + l < n) s_attn[w][64 + l] = e1 * inv;
    }
  }
  __syncthreads();

  // ---- PV: wave w = head w; group g owns columns g, g+4, ...; 8-deep batch ----
  {
    const __bf16* vbp = vpb + (size_t)b * S_LEN * HDIM + w * DH + ll * 4;
    float ax = 0.f, ay = 0.f, az = 0.f, aw2 = 0.f;

    for (int i0 = g; i0 < n; i0 += 32) {   // 8 slots x stride 4
      float  a8[8];
      bf16x4 v8[8];
      float4 e8[8];
#pragma unroll
      for (int s = 0; s < 8; ++s) {
        const int i = i0 + s * 4;
        if (i < n) {
          const int kk = s_list[i];
          a8[s] = s_attn[w][i];
          v8[s] = *(const bf16x4*)(vbp + (size_t)kk * HDIM);
          e8[s] = *(const float4*)(evb2 + kk * DH + ll * 4);
        } else {
          a8[s] = 0.f;
          v8[s] = bf16x4{};
          e8[s] = make_float4(0.f, 0.f, 0.f, 0.f);
        }
      }
#pragma unroll
      for (int s = 0; s < 8; ++s) {
        const float4 vf = b2f4(v8[s]);
        ax  += a8[s] * (vf.x + e8[s].x);
        ay  += a8[s] * (vf.y + e8[s].y);
        az  += a8[s] * (vf.z + e8[s].z);
        aw2 += a8[s] * (vf.w + e8[s].w);
      }
    }
#pragma unroll
    for (int off = 16; off < 64; off <<= 1) {
      ax  += __shfl_xor(ax, off, 64);
      ay  += __shfl_xor(ay, off, 64);
      az  += __shfl_xor(az, off, 64);
      aw2 += __shfl_xor(aw2, off, 64);
    }
    if (g == 0) {
      bf16x4 rr;
      rr[0] = (__bf16)ax; rr[1] = (__bf16)ay;
      rr[2] = (__bf16)az; rr[3] = (__bf16)aw2;
      *(bf16x4*)(xpb + ((size_t)b * S_LEN + q) * HDIM + w * 64 + ll * 4) = rr;
    }
  }
}

// ---------------------------------------------------------------------------
// Output projection (R8-proven): per-wave 32x32 tile, bf16 A and W.
// ---------------------------------------------------------------------------
__global__ __launch_bounds__(256) void gemm_o(
    const __bf16* __restrict__ A, const __bf16* __restrict__ W,
    const float* __restrict__ bias, float* __restrict__ out)
{
  const int w = threadIdx.x >> 6;
  const int tile = blockIdx.x * 4 + w;
  if (tile >= 127) return;
  const int row0 = tile * 32, col0 = blockIdx.y * 32;
  const int lane = threadIdx.x & 63;
  const int r  = lane & 15;
  const int ks = (lane >> 4) << 3;
  const __bf16* Ab = A + (size_t)(row0 + r) * HDIM + ks;
  const __bf16* Wb = W + (size_t)(col0 + r) * HDIM + ks;
  f32x4 acc[2][2] = {};

  bf16x8 ca[2], cw[2];
  ca[0] = *(const bf16x8*)Ab;
  ca[1] = *(const bf16x8*)(Ab + (size_t)16 * HDIM);
  cw[0] = *(const bf16x8*)Wb;
  cw[1] = *(const bf16x8*)(Wb + (size_t)16 * HDIM);
#pragma unroll
  for (int kb = 0; kb < 8; ++kb) {
    bf16x8 na[2], nw[2];
    if (kb < 7) {
      const int off = (kb + 1) * 32;
      na[0] = *(const bf16x8*)(Ab + off);
      na[1] = *(const bf16x8*)(Ab + (size_t)16 * HDIM + off);
      nw[0] = *(const bf16x8*)(Wb + off);
      nw[1] = *(const bf16x8*)(Wb + (size_t)16 * HDIM + off);
    }
#pragma unroll
    for (int mi = 0; mi < 2; ++mi)
#pragma unroll
      for (int ni = 0; ni < 2; ++ni)
        acc[mi][ni] = __builtin_amdgcn_mfma_f32_16x16x32_bf16(
            ca[mi], cw[ni], acc[mi][ni], 0, 0, 0);
    if (kb < 7) {
      ca[0] = na[0]; ca[1] = na[1];
      cw[0] = nw[0]; cw[1] = nw[1];
    }
  }
  const int crow = (lane >> 4) * 4;
  const int ccol = lane & 15;
#pragma unroll
  for (int mi = 0; mi < 2; ++mi)
#pragma unroll
    for (int ni = 0; ni < 2; ++ni) {
      const int oc = col0 + ni * 16 + ccol;
      const float bv = bias[oc];
#pragma unroll
      for (int rg = 0; rg < 4; ++rg)
        out[(size_t)(row0 + mi * 16 + crow + rg) * HDIM + oc] = acc[mi][ni][rg] + bv;
    }
}

extern "C" void kernel_launch(void* const* d_in, const int* in_sizes, int n_in,
                              void* d_out, int out_size, void* d_ws, size_t ws_size,
                              hipStream_t stream) {
  const float* query = (const float*)d_in[0];
  const float* key   = (const float*)d_in[1];
  const float* value = (const float*)d_in[2];
  const int*   graph = (const int*)d_in[3];
  const float* ekt   = (const float*)d_in[4];
  const float* evt   = (const float*)d_in[5];
  const float* eqt   = (const float*)d_in[6];
  const float* Wq = (const float*)d_in[7];  const float* bq = (const float*)d_in[8];
  const float* Wk = (const float*)d_in[9];  const float* bk = (const float*)d_in[10];
  const float* Wv = (const float*)d_in[11]; const float* bv = (const float*)d_in[12];
  const float* Wo = (const float*)d_in[13]; const float* bo = (const float*)d_in[14];
  float* out = (float*)d_out;

  const size_t NE = (size_t)NTOK * HDIM;   // 1,040,384 elems
  char* p = (char*)d_ws;
  __bf16* qpb = (__bf16*)p;         p += NE * 2;
  __bf16* kpb = (__bf16*)p;         p += NE * 2;
  __bf16* vpb = (__bf16*)p;         p += NE * 2;
  __bf16* xpb = (__bf16*)p;         p += NE * 2;
  __bf16* Wqb = (__bf16*)p;         p += (size_t)HDIM * HDIM * 2;
  __bf16* Wkb = (__bf16*)p;         p += (size_t)HDIM * HDIM * 2;
  __bf16* Wvb = (__bf16*)p;         p += (size_t)HDIM * HDIM * 2;
  __bf16* Wob = (__bf16*)p;

  convert_w<<<dim3(256), 256, 0, stream>>>(Wq, Wk, Wv, Wo, Wqb, Wkb, Wvb, Wob);
  gemm_qkv<<<dim3(127, 3), 256, 0, stream>>>(query, key, value,
                                             Wqb, bq, Wkb, bk, Wvb, bv,
                                             qpb, kpb, vpb);
  attn_kernel<<<dim3(NB * S_LEN), 256, 0, stream>>>(qpb, kpb, vpb, graph,
                                                    ekt, evt, eqt, xpb);
  gemm_o<<<dim3(32, 8), 256, 0, stream>>>(xpb, Wob, bo, out);
}